// Round 1
// baseline (422.714 us; speedup 1.0000x reference)
//
#include <hip/hip_runtime.h>
#include <math.h>

#define BB 8
#define NN 65536
#define CC 80
#define TT 32
#define MINPOS 16

// ------------------------------------------------------------------
// K1: per-anchor stats. block = 256 threads = 256 anchors.
//   phase A: decode + IoU vs 32 targets (LDS), max/argmax, pos count
//   phase B: 4 threads/anchor float4 logsumexp over 80 classes -> focal terms
//   phase C: smooth-L1 vs encoded target, write float4 stats + miou
// ------------------------------------------------------------------
__global__ __launch_bounds__(256) void k_peranchor(
    const float* __restrict__ cls, const float* __restrict__ reg,
    const float* __restrict__ anchors, const float* __restrict__ tboxes,
    const int* __restrict__ tlabels,
    float4* __restrict__ stats, float* __restrict__ miou_out,
    int* __restrict__ posCnt)
{
    const int b   = blockIdx.y;
    const int a0  = blockIdx.x * 256;
    const int tid = threadIdx.x;
    const int a   = a0 + tid;

    __shared__ float4 tb[TT];
    __shared__ float  tarea[TT];
    __shared__ int    tl[TT];
    __shared__ int    s_midx[256];
    __shared__ float  s_flp[256];
    __shared__ float  s_fln[256];
    __shared__ int    s_pc;

    if (tid < TT) {
        float4 t = ((const float4*)(tboxes + (size_t)b * TT * 4))[tid];
        tb[tid] = t;
        tarea[tid] = (t.z - t.x) * (t.w - t.y);
        tl[tid] = tlabels[b * TT + tid];
    }
    if (tid == 0) s_pc = 0;
    __syncthreads();

    // ---- phase A: decode + IoU ----
    float4 r  = ((const float4*)reg)[(size_t)b * NN + a];
    float4 an = ((const float4*)anchors)[a];
    float aw = an.z - an.x, ah = an.w - an.y;
    float acx = an.x + 0.5f * aw, acy = an.y + 0.5f * ah;
    float cx = r.x * aw + acx, cy = r.y * ah + acy;
    float w = expf(r.z) * aw, h = expf(r.w) * ah;
    float dx0 = cx - 0.5f * w, dy0 = cy - 0.5f * h;
    float dx1 = cx + 0.5f * w, dy1 = cy + 0.5f * h;
    float areaA = (dx1 - dx0) * (dy1 - dy0);

    float mi = -1.0f; int mix = 0;
    #pragma unroll 8
    for (int t = 0; t < TT; ++t) {
        float4 bx = tb[t];
        float ltx = fmaxf(dx0, bx.x), lty = fmaxf(dy0, bx.y);
        float rbx = fminf(dx1, bx.z), rby = fminf(dy1, bx.w);
        float iw = fmaxf(rbx - ltx, 0.0f), ih = fmaxf(rby - lty, 0.0f);
        float inter = iw * ih;
        float iou = inter / (areaA + tarea[t] - inter + 1e-6f);
        if (iou > mi) { mi = iou; mix = t; }   // strict > : first-occurrence argmax
    }
    s_midx[tid] = mix;
    unsigned long long bal = __ballot(mi >= 0.5f);
    if ((tid & 63) == 0) atomicAdd(&s_pc, __popcll(bal));
    __syncthreads();

    // ---- phase B: logsumexp, 4 threads per anchor ----
    const int sub = tid & 3;
    #pragma unroll
    for (int j = 0; j < 4; ++j) {
        const int al = j * 64 + (tid >> 2);
        const int ag = a0 + al;
        const float4* rowp = (const float4*)(cls + ((size_t)b * NN + ag) * CC);
        float4 v0 = rowp[sub];
        float4 v1 = rowp[sub + 4];
        float4 v2 = rowp[sub + 8];
        float4 v3 = rowp[sub + 12];
        float4 v4 = rowp[sub + 16];
        float mx = fmaxf(fmaxf(fmaxf(v0.x, v0.y), fmaxf(v0.z, v0.w)),
                   fmaxf(fmaxf(fmaxf(v1.x, v1.y), fmaxf(v1.z, v1.w)),
                   fmaxf(fmaxf(fmaxf(v2.x, v2.y), fmaxf(v2.z, v2.w)),
                   fmaxf(fmaxf(fmaxf(v3.x, v3.y), fmaxf(v3.z, v3.w)),
                         fmaxf(fmaxf(v4.x, v4.y), fmaxf(v4.z, v4.w))))));
        float sm = expf(v0.x - mx) + expf(v0.y - mx) + expf(v0.z - mx) + expf(v0.w - mx)
                 + expf(v1.x - mx) + expf(v1.y - mx) + expf(v1.z - mx) + expf(v1.w - mx)
                 + expf(v2.x - mx) + expf(v2.y - mx) + expf(v2.z - mx) + expf(v2.w - mx)
                 + expf(v3.x - mx) + expf(v3.y - mx) + expf(v3.z - mx) + expf(v3.w - mx)
                 + expf(v4.x - mx) + expf(v4.y - mx) + expf(v4.z - mx) + expf(v4.w - mx);
        #pragma unroll
        for (int off = 1; off < 4; off <<= 1) {
            float m2 = __shfl_xor(mx, off);
            float s2 = __shfl_xor(sm, off);
            float nm = fmaxf(mx, m2);
            sm = sm * expf(mx - nm) + s2 * expf(m2 - nm);
            mx = nm;
        }
        if (sub == 0) {
            float lse = mx + logf(sm);
            int midx = s_midx[al];
            int lab = tl[midx];
            float xlab = cls[((size_t)b * NN + ag) * CC + lab];  // L1-hot reread
            float x0 = v0.x;
            float cep = lse - xlab;
            float pt  = expf(-cep);
            float o   = 1.0f - pt;
            s_flp[al] = (lab > 0 ? 0.25f : 0.75f) * o * o * cep;
            float cen = lse - x0;
            float ptn = expf(-cen);
            float on  = 1.0f - ptn;
            s_fln[al] = 0.9f * on * on * on * cen;
        }
    }
    __syncthreads();

    // ---- phase C: smooth-L1 + write out ----
    float4 gt = tb[mix];
    float gw = gt.z - gt.x, gh = gt.w - gt.y;
    float gcx = gt.x + 0.5f * gw, gcy = gt.y + 0.5f * gh;
    float t0 = (gcx - acx) / (aw + 1e-6f);
    float t1 = (gcy - acy) / (ah + 1e-6f);
    float t2 = logf(gw / (aw + 1e-6f));
    float t3 = logf(gh / (ah + 1e-6f));
    float d0 = fabsf(r.x - t0), d1 = fabsf(r.y - t1);
    float d2 = fabsf(r.z - t2), d3 = fabsf(r.w - t3);
    float sl1 = (d0 < 1.0f ? 0.5f * d0 * d0 : d0 - 0.5f)
              + (d1 < 1.0f ? 0.5f * d1 * d1 : d1 - 0.5f)
              + (d2 < 1.0f ? 0.5f * d2 * d2 : d2 - 0.5f)
              + (d3 < 1.0f ? 0.5f * d3 * d3 : d3 - 0.5f);

    stats[(size_t)b * NN + a] = make_float4(s_flp[tid], s_fln[tid], sl1, mi);
    miou_out[(size_t)b * NN + a] = mi;
    if (tid == 0) atomicAdd(&posCnt[b], s_pc);
}

// ------------------------------------------------------------------
// K2 helper: exact k-th-largest over candidate subset via 3-round
// radix select on float bits (values >= 0 so uint order == float order).
// Results left in sh_u[0] (value bits) and sh_s[2] (rem = #ties to take).
// mode: 0 = all anchors, 1 = miou < 0.5, 2 = mask != 1
// ------------------------------------------------------------------
__device__ __forceinline__ void radix_select(
    const float* __restrict__ vals, const unsigned char* __restrict__ mask,
    int mode, int kk, int tid,
    unsigned* hist, int* sh_s, unsigned* sh_u)
{
    if (tid == 0) { sh_u[0] = 0u; sh_u[1] = 0u; sh_s[2] = kk; }
    __syncthreads();
    #pragma unroll
    for (int rnd = 0; rnd < 3; ++rnd) {
        const int sh = (rnd == 0) ? 21 : ((rnd == 1) ? 10 : 0);
        const int NB = (rnd == 2) ? 1024 : 2048;
        hist[tid] = 0u; hist[tid + 1024] = 0u;
        __syncthreads();
        const unsigned pref = sh_u[0], pmask = sh_u[1];
        for (int i = tid; i < NN; i += 1024) {
            bool c = (mode == 0) ? true
                   : (mode == 1) ? (vals[i] < 0.5f)
                                 : (mask[i] != (unsigned char)1);
            if (c) {
                unsigned u = __float_as_uint(vals[i]);
                if ((u & pmask) == pref)
                    atomicAdd(&hist[(u >> sh) & (unsigned)(NB - 1)], 1u);
            }
        }
        __syncthreads();
        if (tid < 64) {
            const int cs = NB / 64;
            const int base = tid * cs;
            int csum = 0;
            for (int j = 0; j < cs; ++j) csum += (int)hist[base + j];
            int sfx = csum;
            #pragma unroll
            for (int off = 1; off < 64; off <<= 1) {
                int o = __shfl_down(sfx, off);
                if (tid + off < 64) sfx += o;
            }
            const int excl = sfx - csum;      // sum over higher lanes' chunks
            const int need = sh_s[2];
            int acc = excl;                   // S(d+1) running from top of chunk
            for (int j = cs - 1; j >= 0; --j) {
                int hcnt = (int)hist[base + j];
                int S = acc + hcnt;           // S(d)
                if (acc < need && S >= need) { sh_s[0] = base + j; sh_s[1] = acc; }
                acc = S;
            }
        }
        __syncthreads();
        if (tid == 0) {
            sh_u[0] |= ((unsigned)sh_s[0]) << sh;
            sh_u[1] |= ((unsigned)(NB - 1)) << sh;
            sh_s[2] -= sh_s[1];               // need -= count strictly greater
        }
        __syncthreads();
    }
}

// ------------------------------------------------------------------
// K2: per-image (8 blocks x 1024) pos/neg mask construction.
// ------------------------------------------------------------------
__global__ __launch_bounds__(1024) void k_select(
    const float* __restrict__ miou_all, unsigned char* __restrict__ mask_all,
    const int* __restrict__ posCnt, int* __restrict__ numpos,
    int* __restrict__ knum, float* __restrict__ accum)
{
    const int b = blockIdx.x;
    const int tid = threadIdx.x;
    const float* miou = miou_all + (size_t)b * NN;
    unsigned char* mask = mask_all + (size_t)b * NN;

    __shared__ unsigned hist[2048];
    __shared__ int sh_s[3];
    __shared__ unsigned sh_u[2];
    __shared__ int wtot[16];
    __shared__ int sh_ties;

    const int pc = posCnt[b];
    const bool fallback = (pc < MINPOS);
    int num_pos;

    if (fallback) {
        // top-16 over all anchors, stable (index-order) ties -> mask=1
        radix_select(miou, mask, 0, MINPOS, tid, hist, sh_s, sh_u);
        const unsigned vb = sh_u[0];
        const int rem = sh_s[2];
        if (tid == 0) sh_ties = 0;
        __syncthreads();
        for (int base = 0; base < NN; base += 1024) {
            const int i = base + tid;
            const unsigned u = __float_as_uint(miou[i]);
            const bool tie = (u == vb);
            unsigned long long bal = __ballot(tie);
            const int wave = tid >> 6, lane = tid & 63;
            if (lane == 0) wtot[wave] = __popcll(bal);
            __syncthreads();
            int wexcl = 0;
            for (int wv = 0; wv < wave; ++wv) wexcl += wtot[wv];
            const int myexcl = sh_ties + wexcl + __popcll(bal & ((1ull << lane) - 1ull));
            const bool sel = (u > vb) || (tie && myexcl < rem);
            mask[i] = sel ? (unsigned char)1 : (unsigned char)0;
            __syncthreads();
            if (tid == 0) { int ts = 0; for (int wv = 0; wv < 16; ++wv) ts += wtot[wv]; sh_ties += ts; }
            __syncthreads();
        }
        num_pos = MINPOS;
    } else {
        num_pos = pc;
    }

    int kk = NN - num_pos;
    if (4 * num_pos < kk) kk = 4 * num_pos;

    radix_select(miou, mask, fallback ? 2 : 1, kk, tid, hist, sh_s, sh_u);
    const unsigned vb = sh_u[0];
    const int rem = sh_s[2];
    if (tid == 0) sh_ties = 0;
    __syncthreads();
    for (int base = 0; base < NN; base += 1024) {
        const int i = base + tid;
        const float v = miou[i];
        const unsigned u = __float_as_uint(v);
        const bool pos = fallback ? (mask[i] == (unsigned char)1) : (v >= 0.5f);
        const bool cand = !pos;
        const bool tie = cand && (u == vb);
        unsigned long long bal = __ballot(tie);
        const int wave = tid >> 6, lane = tid & 63;
        if (lane == 0) wtot[wave] = __popcll(bal);
        __syncthreads();
        int wexcl = 0;
        for (int wv = 0; wv < wave; ++wv) wexcl += wtot[wv];
        const int myexcl = sh_ties + wexcl + __popcll(bal & ((1ull << lane) - 1ull));
        const bool neg = cand && ((u > vb) || (tie && myexcl < rem));
        mask[i] = pos ? (unsigned char)1 : (neg ? (unsigned char)2 : (unsigned char)0);
        __syncthreads();
        if (tid == 0) { int ts = 0; for (int wv = 0; wv < 16; ++wv) ts += wtot[wv]; sh_ties += ts; }
        __syncthreads();
    }

    if (tid == 0) {
        numpos[b] = num_pos;
        knum[b]   = kk;
        accum[b * 3 + 0] = 0.0f;
        accum[b * 3 + 1] = 0.0f;
        accum[b * 3 + 2] = 0.0f;
    }
}

// ------------------------------------------------------------------
// K3: masked reduction into per-image accumulators.
// ------------------------------------------------------------------
__global__ __launch_bounds__(256) void k_reduce(
    const float4* __restrict__ stats, const unsigned char* __restrict__ mask,
    float* __restrict__ accum)
{
    const int b = blockIdx.y;
    const size_t idx = (size_t)b * NN + blockIdx.x * 256 + threadIdx.x;
    float4 s = stats[idx];
    unsigned char m = mask[idx];
    float cp = (m == 1) ? s.x : 0.0f;
    float cn = (m == 2) ? s.y : 0.0f;
    float rg = (m == 1) ? s.z : 0.0f;
    #pragma unroll
    for (int off = 32; off > 0; off >>= 1) {
        cp += __shfl_down(cp, off);
        cn += __shfl_down(cn, off);
        rg += __shfl_down(rg, off);
    }
    __shared__ float wcp[4], wcn[4], wrg[4];
    const int lane = threadIdx.x & 63, wave = threadIdx.x >> 6;
    if (lane == 0) { wcp[wave] = cp; wcn[wave] = cn; wrg[wave] = rg; }
    __syncthreads();
    if (threadIdx.x == 0) {
        atomicAdd(&accum[b * 3 + 0], wcp[0] + wcp[1] + wcp[2] + wcp[3]);
        atomicAdd(&accum[b * 3 + 1], wcn[0] + wcn[1] + wcn[2] + wcn[3]);
        atomicAdd(&accum[b * 3 + 2], wrg[0] + wrg[1] + wrg[2] + wrg[3]);
    }
}

// ------------------------------------------------------------------
// K4: finalize the 4 scalar outputs.
// ------------------------------------------------------------------
__global__ void k_finalize(const float* __restrict__ accum,
                           const int* __restrict__ numpos,
                           const int* __restrict__ knum,
                           float* __restrict__ out)
{
    if (threadIdx.x == 0 && blockIdx.x == 0) {
        float clsf = 0.0f, regf = 0.0f;
        int tp = 0;
        for (int b = 0; b < BB; ++b) {
            float cp = accum[b * 3 + 0];
            float cn = accum[b * 3 + 1];
            float rs = accum[b * 3 + 2];
            int np = numpos[b], kk = knum[b];
            int ts = np + kk; if (ts < 1) ts = 1;
            clsf += (cp + cn) / (float)ts;
            regf += rs / ((float)np + 1e-6f);
            tp += np;
        }
        clsf *= (1.0f / BB);
        regf *= (1.0f / BB);
        float reg_final = (tp > 0) ? regf : 0.0f;
        float rw = fminf(1.0f, (float)tp / (100.0f * BB));
        out[0] = clsf + rw * reg_final;
        out[1] = clsf;
        out[2] = reg_final;
        out[3] = (float)tp;
    }
}

extern "C" void kernel_launch(void* const* d_in, const int* in_sizes, int n_in,
                              void* d_out, int out_size, void* d_ws, size_t ws_size,
                              hipStream_t stream)
{
    const float* cls     = (const float*)d_in[0];
    const float* reg     = (const float*)d_in[1];
    const float* anchors = (const float*)d_in[2];
    const float* tboxes  = (const float*)d_in[3];
    const int*   tlabels = (const int*)d_in[4];

    char* ws = (char*)d_ws;
    float4*        stats  = (float4*)ws;                              // 8 MB
    float*         miou   = (float*)(ws + (size_t)BB * NN * 16);      // 2 MB
    unsigned char* mask   = (unsigned char*)(ws + (size_t)BB * NN * 20); // 512 KB
    char* tail = ws + (size_t)BB * NN * 21;                           // 64B-aligned
    int*   posCnt = (int*)tail;
    int*   numpos = (int*)(tail + 64);
    int*   knum   = (int*)(tail + 128);
    float* accum  = (float*)(tail + 192);
    float* out    = (float*)d_out;

    // posCnt must be zero before K1 atomics (ws is re-poisoned every launch)
    hipMemsetAsync(posCnt, 0, 64, stream);

    dim3 g1(NN / 256, BB);
    k_peranchor<<<g1, 256, 0, stream>>>(cls, reg, anchors, tboxes, tlabels,
                                        stats, miou, posCnt);
    k_select<<<BB, 1024, 0, stream>>>(miou, mask, posCnt, numpos, knum, accum);
    dim3 g3(NN / 256, BB);
    k_reduce<<<g3, 256, 0, stream>>>(stats, mask, accum);
    k_finalize<<<1, 64, 0, stream>>>(accum, numpos, knum, out);
}

// Round 2
// 354.642 us; speedup vs baseline: 1.1919x; 1.1919x over previous
//
#include <hip/hip_runtime.h>
#include <math.h>

#define BB 8
#define NN 65536
#define CC 80
#define TT 32
#define MINPOS 16
#define TIECAP 4096

// ------------------------------------------------------------------
// K1a (k_prep): decode + IoU + smooth-L1 + per-image posCnt + coarse
// 512-bin histogram of miou float bits [31:21]. Grid (N/256, B).
// ------------------------------------------------------------------
__global__ __launch_bounds__(256) void k_prep(
    const float* __restrict__ reg, const float* __restrict__ anchors,
    const float* __restrict__ tboxes, const int* __restrict__ tlabels,
    float* __restrict__ miou_out, float* __restrict__ sl1_out,
    unsigned char* __restrict__ lbl_out,
    unsigned* __restrict__ gHist, int* __restrict__ posCnt)
{
    const int b   = blockIdx.y;
    const int tid = threadIdx.x;
    const int a   = blockIdx.x * 256 + tid;

    __shared__ float4 tb[TT];
    __shared__ float  tarea[TT];
    __shared__ int    tl[TT];
    __shared__ unsigned lh[512];
    __shared__ int    s_pc;

    if (tid < TT) {
        float4 t = ((const float4*)(tboxes + (size_t)b * TT * 4))[tid];
        tb[tid] = t;
        tarea[tid] = (t.z - t.x) * (t.w - t.y);
        tl[tid] = tlabels[b * TT + tid];
    }
    lh[tid] = 0u; lh[tid + 256] = 0u;
    if (tid == 0) s_pc = 0;
    __syncthreads();

    float4 r  = ((const float4*)reg)[(size_t)b * NN + a];
    float4 an = ((const float4*)anchors)[a];
    float aw = an.z - an.x, ah = an.w - an.y;
    float acx = an.x + 0.5f * aw, acy = an.y + 0.5f * ah;
    float cx = r.x * aw + acx, cy = r.y * ah + acy;
    float w = expf(r.z) * aw, hh = expf(r.w) * ah;
    float dx0 = cx - 0.5f * w, dy0 = cy - 0.5f * hh;
    float dx1 = cx + 0.5f * w, dy1 = cy + 0.5f * hh;
    float areaA = (dx1 - dx0) * (dy1 - dy0);

    float mi = -1.0f; int mix = 0;
    #pragma unroll 8
    for (int t = 0; t < TT; ++t) {
        float4 bx = tb[t];
        float ltx = fmaxf(dx0, bx.x), lty = fmaxf(dy0, bx.y);
        float rbx = fminf(dx1, bx.z), rby = fminf(dy1, bx.w);
        float iw = fmaxf(rbx - ltx, 0.0f), ih = fmaxf(rby - lty, 0.0f);
        float inter = iw * ih;
        float iou = inter / (areaA + tarea[t] - inter + 1e-6f);
        if (iou > mi) { mi = iou; mix = t; }   // strict > : first-occurrence argmax
    }

    // smooth-L1 vs encoded matched target
    float4 gt = tb[mix];
    float gw = gt.z - gt.x, gh = gt.w - gt.y;
    float gcx = gt.x + 0.5f * gw, gcy = gt.y + 0.5f * gh;
    float t0 = (gcx - acx) / (aw + 1e-6f);
    float t1 = (gcy - acy) / (ah + 1e-6f);
    float t2 = logf(gw / (aw + 1e-6f));
    float t3 = logf(gh / (ah + 1e-6f));
    float d0 = fabsf(r.x - t0), d1 = fabsf(r.y - t1);
    float d2 = fabsf(r.z - t2), d3 = fabsf(r.w - t3);
    float sl1v = (d0 < 1.0f ? 0.5f * d0 * d0 : d0 - 0.5f)
               + (d1 < 1.0f ? 0.5f * d1 * d1 : d1 - 0.5f)
               + (d2 < 1.0f ? 0.5f * d2 * d2 : d2 - 0.5f)
               + (d3 < 1.0f ? 0.5f * d3 * d3 : d3 - 0.5f);

    miou_out[(size_t)b * NN + a] = mi;
    sl1_out[(size_t)b * NN + a]  = sl1v;
    lbl_out[(size_t)b * NN + a]  = (unsigned char)tl[mix];

    atomicAdd(&lh[__float_as_uint(mi) >> 21], 1u);   // mi in [0,1] -> bin <= 508
    unsigned long long bal = __ballot(mi >= 0.5f);
    if ((tid & 63) == 0) atomicAdd(&s_pc, __popcll(bal));
    __syncthreads();

    if (lh[tid])       atomicAdd(&gHist[b * 512 + tid],       lh[tid]);
    if (lh[tid + 256]) atomicAdd(&gHist[b * 512 + tid + 256], lh[tid + 256]);
    if (tid == 0) atomicAdd(&posCnt[b], s_pc);
}

// ------------------------------------------------------------------
// K1b (k_cls): the 167 MB kernel. 4 threads/anchor float4 logsumexp.
// Block 256 = 64 anchors; grid (N/64, B). No LDS, low VGPR.
// ------------------------------------------------------------------
__global__ __launch_bounds__(256) void k_cls(
    const float* __restrict__ cls, const unsigned char* __restrict__ lbl,
    float* __restrict__ flp_out, float* __restrict__ fln_out)
{
    const int b   = blockIdx.y;
    const int al  = threadIdx.x >> 2;
    const int sub = threadIdx.x & 3;
    const int ag  = blockIdx.x * 64 + al;
    const size_t row = (size_t)b * NN + ag;
    const float4* rowp = (const float4*)(cls + row * CC);

    float4 v0 = rowp[sub];
    float4 v1 = rowp[sub + 4];
    float4 v2 = rowp[sub + 8];
    float4 v3 = rowp[sub + 12];
    float4 v4 = rowp[sub + 16];

    float mx = fmaxf(fmaxf(fmaxf(v0.x, v0.y), fmaxf(v0.z, v0.w)),
               fmaxf(fmaxf(fmaxf(v1.x, v1.y), fmaxf(v1.z, v1.w)),
               fmaxf(fmaxf(fmaxf(v2.x, v2.y), fmaxf(v2.z, v2.w)),
               fmaxf(fmaxf(fmaxf(v3.x, v3.y), fmaxf(v3.z, v3.w)),
                     fmaxf(fmaxf(v4.x, v4.y), fmaxf(v4.z, v4.w))))));
    float sm = expf(v0.x - mx) + expf(v0.y - mx) + expf(v0.z - mx) + expf(v0.w - mx)
             + expf(v1.x - mx) + expf(v1.y - mx) + expf(v1.z - mx) + expf(v1.w - mx)
             + expf(v2.x - mx) + expf(v2.y - mx) + expf(v2.z - mx) + expf(v2.w - mx)
             + expf(v3.x - mx) + expf(v3.y - mx) + expf(v3.z - mx) + expf(v3.w - mx)
             + expf(v4.x - mx) + expf(v4.y - mx) + expf(v4.z - mx) + expf(v4.w - mx);
    #pragma unroll
    for (int off = 1; off < 4; off <<= 1) {
        float m2 = __shfl_xor(mx, off);
        float s2 = __shfl_xor(sm, off);
        float nm = fmaxf(mx, m2);
        sm = sm * expf(mx - nm) + s2 * expf(m2 - nm);
        mx = nm;
    }
    if (sub == 0) {
        float lse = mx + logf(sm);
        int lab = (int)lbl[row];
        float xlab = cls[row * CC + lab];   // L1-hot reread
        float x0 = v0.x;
        float cep = lse - xlab;
        float pt  = expf(-cep);
        float o   = 1.0f - pt;
        flp_out[row] = (lab > 0 ? 0.25f : 0.75f) * o * o * cep;
        float cen = lse - x0;
        float ptn = expf(-cen);
        float on  = 1.0f - ptn;
        fln_out[row] = 0.9f * on * on * on * cen;
    }
}

// ------------------------------------------------------------------
// scan over an LDS histogram: find bin d s.t. (count strictly above d)
// < need <= (count above + h[d]). sh_s[2]=need on entry; writes
// sh_s[0]=bin, sh_s[1]=count strictly above. Proven in R1.
// ------------------------------------------------------------------
__device__ __forceinline__ void scan_hist64(unsigned* hist, int NB, int tid, int* sh_s)
{
    if (tid < 64) {
        const int cs = NB / 64;
        const int base = tid * cs;
        int csum = 0;
        for (int j = 0; j < cs; ++j) csum += (int)hist[base + j];
        int sfx = csum;
        #pragma unroll
        for (int off = 1; off < 64; off <<= 1) {
            int o = __shfl_down(sfx, off);
            if (tid + off < 64) sfx += o;
        }
        const int excl = sfx - csum;
        const int need = sh_s[2];
        int acc = excl;
        for (int j = cs - 1; j >= 0; --j) {
            int hcnt = (int)hist[base + j];
            int S = acc + hcnt;
            if (acc < need && S >= need) { sh_s[0] = base + j; sh_s[1] = acc; }
            acc = S;
        }
    }
}

// R1-proven 3-round radix select (fallback path only).
__device__ __forceinline__ void radix_select(
    const float* __restrict__ vals, const unsigned char* __restrict__ mask,
    int mode, int kk, int tid,
    unsigned* hist, int* sh_s, unsigned* sh_u)
{
    if (tid == 0) { sh_u[0] = 0u; sh_u[1] = 0u; sh_s[2] = kk; }
    __syncthreads();
    #pragma unroll
    for (int rnd = 0; rnd < 3; ++rnd) {
        const int sh = (rnd == 0) ? 21 : ((rnd == 1) ? 10 : 0);
        const int NB = (rnd == 2) ? 1024 : 2048;
        hist[tid] = 0u; hist[tid + 1024] = 0u;
        __syncthreads();
        const unsigned pref = sh_u[0], pmask = sh_u[1];
        for (int i = tid; i < NN; i += 1024) {
            bool c = (mode == 0) ? true
                   : (mode == 1) ? (vals[i] < 0.5f)
                                 : (mask[i] != (unsigned char)1);
            if (c) {
                unsigned u = __float_as_uint(vals[i]);
                if ((u & pmask) == pref)
                    atomicAdd(&hist[(u >> sh) & (unsigned)(NB - 1)], 1u);
            }
        }
        __syncthreads();
        scan_hist64(hist, NB, tid, sh_s);
        __syncthreads();
        if (tid == 0) {
            sh_u[0] |= ((unsigned)sh_s[0]) << sh;
            sh_u[1] |= ((unsigned)(NB - 1)) << sh;
            sh_s[2] -= sh_s[1];
        }
        __syncthreads();
    }
}

// ------------------------------------------------------------------
// K2 (k_select): per-image selection + fused masked reduction.
// Fast path: coarse bin precomputed in k_prep -> 1 histogram pass +
// 1 fused reduce pass, ties via LDS list (no inner barriers).
// ------------------------------------------------------------------
__global__ __launch_bounds__(1024) void k_select(
    const float* __restrict__ miou_all,
    const float* __restrict__ flp_all, const float* __restrict__ fln_all,
    const float* __restrict__ sl1_all,
    const unsigned* __restrict__ gHist, const int* __restrict__ posCnt,
    unsigned char* __restrict__ mask_all,
    int* __restrict__ numpos, int* __restrict__ knum, float* __restrict__ accum)
{
    const int b = blockIdx.x;
    const int tid = threadIdx.x;
    const float* miou = miou_all + (size_t)b * NN;
    const float* flp  = flp_all  + (size_t)b * NN;
    const float* fln  = fln_all  + (size_t)b * NN;
    const float* sl1  = sl1_all  + (size_t)b * NN;
    unsigned char* mask = mask_all + (size_t)b * NN;

    __shared__ unsigned hist[2048];
    __shared__ int sh_s[3];
    __shared__ unsigned sh_u[2];
    __shared__ int wtot[16];
    __shared__ int sh_ties;
    __shared__ unsigned tieU[TIECAP];
    __shared__ int tieI[TIECAP];
    __shared__ int sh_tc;
    __shared__ float wred[48];

    const int pc = posCnt[b];
    const bool fallback = (pc < MINPOS);
    float accP = 0.0f, accN = 0.0f, accR = 0.0f;
    int np, kk;

    if (!fallback) {
        np = pc;
        kk = NN - np; if (4 * np < kk) kk = 4 * np;

        // coarse pivot from precomputed histogram (candidate bins <= 503:
        // 0.5f == 0x3F000000 -> bin 504, boundary is exact)
        if (tid < 512) {
            unsigned v = gHist[b * 512 + tid];
            hist[tid] = (tid <= 503) ? v : 0u;
        }
        if (tid == 0) { sh_s[2] = kk; sh_tc = 0; }
        __syncthreads();
        scan_hist64(hist, 512, tid, sh_s);
        __syncthreads();
        const unsigned pivotBin = (unsigned)sh_s[0];
        if (tid == 0) sh_s[2] -= sh_s[1];
        hist[tid] = 0u; hist[tid + 1024] = 0u;
        __syncthreads();

        // one full-N histogram pass over bits [20:10] within the coarse bin
        for (int i = tid; i < NN; i += 1024) {
            unsigned u = __float_as_uint(miou[i]);
            if ((u >> 21) == pivotBin) atomicAdd(&hist[(u >> 10) & 2047u], 1u);
        }
        __syncthreads();
        scan_hist64(hist, 2048, tid, sh_s);
        __syncthreads();
        const unsigned pivot22 = (pivotBin << 11) | (unsigned)sh_s[0];
        const int rem = sh_s[2] - sh_s[1];   // ties (by value desc, idx asc) to accept

        // fused selection + reduction pass (no barriers inside)
        for (int i = tid; i < NN; i += 1024) {
            float v = miou[i];
            unsigned u = __float_as_uint(v);
            if (v >= 0.5f) { accP += flp[i]; accR += sl1[i]; }
            else {
                unsigned p = u >> 10;
                if (p > pivot22) accN += fln[i];
                else if (p == pivot22) {
                    int t = atomicAdd(&sh_tc, 1);
                    if (t < TIECAP) { tieU[t] = u; tieI[t] = i; }
                }
            }
        }
        __syncthreads();
        int tc = sh_tc; if (tc > TIECAP) tc = TIECAP;
        for (int t = tid; t < tc; t += 1024) {
            unsigned ut = tieU[t]; int it = tieI[t];
            int rank = 0;
            for (int j = 0; j < tc; ++j) {
                unsigned uj = tieU[j]; int ij = tieI[j];
                rank += (uj > ut || (uj == ut && ij < it)) ? 1 : 0;
            }
            if (rank < rem) accN += fln[it];
        }
    } else {
        // ---- fallback (pc < MINPOS) — R1-proven slow path, never hit here ----
        radix_select(miou, mask, 0, MINPOS, tid, hist, sh_s, sh_u);
        {
            const unsigned vb = sh_u[0];
            const int rem = sh_s[2];
            if (tid == 0) sh_ties = 0;
            __syncthreads();
            for (int base = 0; base < NN; base += 1024) {
                const int i = base + tid;
                const unsigned u = __float_as_uint(miou[i]);
                const bool tie = (u == vb);
                unsigned long long bal = __ballot(tie);
                const int wave = tid >> 6, lane = tid & 63;
                if (lane == 0) wtot[wave] = __popcll(bal);
                __syncthreads();
                int wexcl = 0;
                for (int wv = 0; wv < wave; ++wv) wexcl += wtot[wv];
                const int myexcl = sh_ties + wexcl + __popcll(bal & ((1ull << lane) - 1ull));
                const bool sel = (u > vb) || (tie && myexcl < rem);
                mask[i] = sel ? (unsigned char)1 : (unsigned char)0;
                __syncthreads();
                if (tid == 0) { int ts = 0; for (int wv = 0; wv < 16; ++wv) ts += wtot[wv]; sh_ties += ts; }
                __syncthreads();
            }
        }
        np = MINPOS;
        kk = NN - np; if (4 * np < kk) kk = 4 * np;
        radix_select(miou, mask, 2, kk, tid, hist, sh_s, sh_u);
        {
            const unsigned vb = sh_u[0];
            const int rem = sh_s[2];
            if (tid == 0) sh_ties = 0;
            __syncthreads();
            for (int base = 0; base < NN; base += 1024) {
                const int i = base + tid;
                const unsigned u = __float_as_uint(miou[i]);
                const bool pos = (mask[i] == (unsigned char)1);
                const bool cand = !pos;
                const bool tie = cand && (u == vb);
                unsigned long long bal = __ballot(tie);
                const int wave = tid >> 6, lane = tid & 63;
                if (lane == 0) wtot[wave] = __popcll(bal);
                __syncthreads();
                int wexcl = 0;
                for (int wv = 0; wv < wave; ++wv) wexcl += wtot[wv];
                const int myexcl = sh_ties + wexcl + __popcll(bal & ((1ull << lane) - 1ull));
                const bool neg = cand && ((u > vb) || (tie && myexcl < rem));
                mask[i] = pos ? (unsigned char)1 : (neg ? (unsigned char)2 : (unsigned char)0);
                __syncthreads();
                if (tid == 0) { int ts = 0; for (int wv = 0; wv < 16; ++wv) ts += wtot[wv]; sh_ties += ts; }
                __syncthreads();
            }
        }
        for (int i = tid; i < NN; i += 1024) {
            unsigned char m = mask[i];
            if (m == (unsigned char)1) { accP += flp[i]; accR += sl1[i]; }
            else if (m == (unsigned char)2) accN += fln[i];
        }
    }

    // block-wide reduction (single block per image -> plain stores)
    #pragma unroll
    for (int off = 32; off > 0; off >>= 1) {
        accP += __shfl_down(accP, off);
        accN += __shfl_down(accN, off);
        accR += __shfl_down(accR, off);
    }
    const int lane = tid & 63, wave = tid >> 6;
    if (lane == 0) { wred[wave] = accP; wred[wave + 16] = accN; wred[wave + 32] = accR; }
    __syncthreads();
    if (tid == 0) {
        float sP = 0.0f, sN = 0.0f, sR = 0.0f;
        for (int w = 0; w < 16; ++w) { sP += wred[w]; sN += wred[w + 16]; sR += wred[w + 32]; }
        accum[b * 3 + 0] = sP;
        accum[b * 3 + 1] = sN;
        accum[b * 3 + 2] = sR;
        numpos[b] = np;
        knum[b] = kk;
    }
}

// ------------------------------------------------------------------
// K4: finalize the 4 scalar outputs.
// ------------------------------------------------------------------
__global__ void k_finalize(const float* __restrict__ accum,
                           const int* __restrict__ numpos,
                           const int* __restrict__ knum,
                           float* __restrict__ out)
{
    if (threadIdx.x == 0 && blockIdx.x == 0) {
        float clsf = 0.0f, regf = 0.0f;
        int tp = 0;
        for (int b = 0; b < BB; ++b) {
            float cp = accum[b * 3 + 0];
            float cn = accum[b * 3 + 1];
            float rs = accum[b * 3 + 2];
            int np = numpos[b], kk = knum[b];
            int ts = np + kk; if (ts < 1) ts = 1;
            clsf += (cp + cn) / (float)ts;
            regf += rs / ((float)np + 1e-6f);
            tp += np;
        }
        clsf *= (1.0f / BB);
        regf *= (1.0f / BB);
        float reg_final = (tp > 0) ? regf : 0.0f;
        float rw = fminf(1.0f, (float)tp / (100.0f * BB));
        out[0] = clsf + rw * reg_final;
        out[1] = clsf;
        out[2] = reg_final;
        out[3] = (float)tp;
    }
}

extern "C" void kernel_launch(void* const* d_in, const int* in_sizes, int n_in,
                              void* d_out, int out_size, void* d_ws, size_t ws_size,
                              hipStream_t stream)
{
    const float* cls     = (const float*)d_in[0];
    const float* reg     = (const float*)d_in[1];
    const float* anchors = (const float*)d_in[2];
    const float* tboxes  = (const float*)d_in[3];
    const int*   tlabels = (const int*)d_in[4];

    const size_t PL = (size_t)BB * NN * 4;   // one float plane = 2 MB
    char* ws = (char*)d_ws;
    float* flp  = (float*)(ws);
    float* fln  = (float*)(ws + PL);
    float* sl1  = (float*)(ws + 2 * PL);
    float* miou = (float*)(ws + 3 * PL);
    unsigned char* lbl  = (unsigned char*)(ws + 4 * PL);            // 512 KB
    unsigned char* mask = (unsigned char*)(ws + 4 * PL + PL / 4);   // 512 KB (fallback only)
    char* tail = ws + 4 * PL + PL / 2;
    unsigned* gHist = (unsigned*)tail;                // 8*512*4 = 16 KB
    int*   posCnt = (int*)(tail + 16384);             // 32 B
    int*   numpos = (int*)(tail + 16384 + 64);
    int*   knum   = (int*)(tail + 16384 + 128);
    float* accum  = (float*)(tail + 16384 + 192);
    float* out    = (float*)d_out;

    // gHist + posCnt must start zeroed (ws re-poisoned each launch)
    hipMemsetAsync(gHist, 0, 16384 + 64, stream);

    k_prep<<<dim3(NN / 256, BB), 256, 0, stream>>>(reg, anchors, tboxes, tlabels,
                                                   miou, sl1, lbl, gHist, posCnt);
    k_cls<<<dim3(NN / 64, BB), 256, 0, stream>>>(cls, lbl, flp, fln);
    k_select<<<BB, 1024, 0, stream>>>(miou, flp, fln, sl1, gHist, posCnt, mask,
                                      numpos, knum, accum);
    k_finalize<<<1, 64, 0, stream>>>(accum, numpos, knum, out);
}

// Round 3
// 327.457 us; speedup vs baseline: 1.2909x; 1.0830x over previous
//
#include <hip/hip_runtime.h>
#include <math.h>

#define BB 8
#define NN 65536
#define CC 80
#define TT 32
#define MINPOS 16
#define TIECAP 4096

// ------------------------------------------------------------------
// K1 (k_prep): decode + IoU + smooth-L1 + per-image posCnt + coarse
// 512-bin histogram of miou float bits [31:21]. Grid (N/256, B).
// ------------------------------------------------------------------
__global__ __launch_bounds__(256) void k_prep(
    const float* __restrict__ reg, const float* __restrict__ anchors,
    const float* __restrict__ tboxes, const int* __restrict__ tlabels,
    float* __restrict__ miou_out, float* __restrict__ sl1_out,
    unsigned char* __restrict__ lbl_out,
    unsigned* __restrict__ gHist, int* __restrict__ posCnt)
{
    const int b   = blockIdx.y;
    const int tid = threadIdx.x;
    const int a   = blockIdx.x * 256 + tid;

    __shared__ float4 tb[TT];
    __shared__ float  tarea[TT];
    __shared__ int    tl[TT];
    __shared__ unsigned lh[512];
    __shared__ int    s_pc;

    if (tid < TT) {
        float4 t = ((const float4*)(tboxes + (size_t)b * TT * 4))[tid];
        tb[tid] = t;
        tarea[tid] = (t.z - t.x) * (t.w - t.y);
        tl[tid] = tlabels[b * TT + tid];
    }
    lh[tid] = 0u; lh[tid + 256] = 0u;
    if (tid == 0) s_pc = 0;
    __syncthreads();

    float4 r  = ((const float4*)reg)[(size_t)b * NN + a];
    float4 an = ((const float4*)anchors)[a];
    float aw = an.z - an.x, ah = an.w - an.y;
    float acx = an.x + 0.5f * aw, acy = an.y + 0.5f * ah;
    float cx = r.x * aw + acx, cy = r.y * ah + acy;
    float w = expf(r.z) * aw, hh = expf(r.w) * ah;
    float dx0 = cx - 0.5f * w, dy0 = cy - 0.5f * hh;
    float dx1 = cx + 0.5f * w, dy1 = cy + 0.5f * hh;
    float areaA = (dx1 - dx0) * (dy1 - dy0);

    float mi = -1.0f; int mix = 0;
    #pragma unroll 8
    for (int t = 0; t < TT; ++t) {
        float4 bx = tb[t];
        float ltx = fmaxf(dx0, bx.x), lty = fmaxf(dy0, bx.y);
        float rbx = fminf(dx1, bx.z), rby = fminf(dy1, bx.w);
        float iw = fmaxf(rbx - ltx, 0.0f), ih = fmaxf(rby - lty, 0.0f);
        float inter = iw * ih;
        float iou = inter / (areaA + tarea[t] - inter + 1e-6f);
        if (iou > mi) { mi = iou; mix = t; }   // strict > : first-occurrence argmax
    }

    // smooth-L1 vs encoded matched target
    float4 gt = tb[mix];
    float gw = gt.z - gt.x, gh = gt.w - gt.y;
    float gcx = gt.x + 0.5f * gw, gcy = gt.y + 0.5f * gh;
    float t0 = (gcx - acx) / (aw + 1e-6f);
    float t1 = (gcy - acy) / (ah + 1e-6f);
    float t2 = logf(gw / (aw + 1e-6f));
    float t3 = logf(gh / (ah + 1e-6f));
    float d0 = fabsf(r.x - t0), d1 = fabsf(r.y - t1);
    float d2 = fabsf(r.z - t2), d3 = fabsf(r.w - t3);
    float sl1v = (d0 < 1.0f ? 0.5f * d0 * d0 : d0 - 0.5f)
               + (d1 < 1.0f ? 0.5f * d1 * d1 : d1 - 0.5f)
               + (d2 < 1.0f ? 0.5f * d2 * d2 : d2 - 0.5f)
               + (d3 < 1.0f ? 0.5f * d3 * d3 : d3 - 0.5f);

    miou_out[(size_t)b * NN + a] = mi;
    sl1_out[(size_t)b * NN + a]  = sl1v;
    lbl_out[(size_t)b * NN + a]  = (unsigned char)tl[mix];

    atomicAdd(&lh[__float_as_uint(mi) >> 21], 1u);   // mi in [0,1] -> bin <= 508
    unsigned long long bal = __ballot(mi >= 0.5f);
    if ((tid & 63) == 0) atomicAdd(&s_pc, __popcll(bal));
    __syncthreads();

    if (lh[tid])       atomicAdd(&gHist[b * 512 + tid],       lh[tid]);
    if (lh[tid + 256]) atomicAdd(&gHist[b * 512 + tid + 256], lh[tid + 256]);
    if (tid == 0) atomicAdd(&posCnt[b], s_pc);
}

// ------------------------------------------------------------------
// scan over an LDS histogram: find bin d s.t. (count strictly above d)
// < need <= (count above + h[d]). sh_s[2]=need on entry; writes
// sh_s[0]=bin, sh_s[1]=count strictly above. Proven R1/R2.
// ------------------------------------------------------------------
__device__ __forceinline__ void scan_hist64(unsigned* hist, int NB, int tid, int* sh_s)
{
    if (tid < 64) {
        const int cs = NB / 64;
        const int base = tid * cs;
        int csum = 0;
        for (int j = 0; j < cs; ++j) csum += (int)hist[base + j];
        int sfx = csum;
        #pragma unroll
        for (int off = 1; off < 64; off <<= 1) {
            int o = __shfl_down(sfx, off);
            if (tid + off < 64) sfx += o;
        }
        const int excl = sfx - csum;
        const int need = sh_s[2];
        int acc = excl;
        for (int j = cs - 1; j >= 0; --j) {
            int hcnt = (int)hist[base + j];
            int S = acc + hcnt;
            if (acc < need && S >= need) { sh_s[0] = base + j; sh_s[1] = acc; }
            acc = S;
        }
    }
}

// R1-proven 3-round radix select (fallback path only).
__device__ __forceinline__ void radix_select(
    const float* __restrict__ vals, const unsigned char* __restrict__ mask,
    int mode, int kk, int tid,
    unsigned* hist, int* sh_s, unsigned* sh_u)
{
    if (tid == 0) { sh_u[0] = 0u; sh_u[1] = 0u; sh_s[2] = kk; }
    __syncthreads();
    #pragma unroll
    for (int rnd = 0; rnd < 3; ++rnd) {
        const int sh = (rnd == 0) ? 21 : ((rnd == 1) ? 10 : 0);
        const int NB = (rnd == 2) ? 1024 : 2048;
        hist[tid] = 0u; hist[tid + 1024] = 0u;
        __syncthreads();
        const unsigned pref = sh_u[0], pmask = sh_u[1];
        for (int i = tid; i < NN; i += 1024) {
            bool c = (mode == 0) ? true
                   : (mode == 1) ? (vals[i] < 0.5f)
                                 : (mask[i] != (unsigned char)1);
            if (c) {
                unsigned u = __float_as_uint(vals[i]);
                if ((u & pmask) == pref)
                    atomicAdd(&hist[(u >> sh) & (unsigned)(NB - 1)], 1u);
            }
        }
        __syncthreads();
        scan_hist64(hist, NB, tid, sh_s);
        __syncthreads();
        if (tid == 0) {
            sh_u[0] |= ((unsigned)sh_s[0]) << sh;
            sh_u[1] |= ((unsigned)(NB - 1)) << sh;
            sh_s[2] -= sh_s[1];
        }
        __syncthreads();
    }
}

// ------------------------------------------------------------------
// K2 (k_select): per-image selection -> compacted anchor list.
// entry u32 = anchor(16b) | isPos<<16 | label<<17.
// Also computes sl1-sum over positives and pre-zeroes accP/accN.
// ------------------------------------------------------------------
__global__ __launch_bounds__(1024) void k_select(
    const float* __restrict__ miou_all, const float* __restrict__ sl1_all,
    const unsigned char* __restrict__ lbl_all,
    const unsigned* __restrict__ gHist, const int* __restrict__ posCnt,
    unsigned char* __restrict__ mask_all,
    unsigned* __restrict__ list_all, int* __restrict__ listCnt,
    int* __restrict__ numpos, int* __restrict__ knum, float* __restrict__ accum)
{
    const int b = blockIdx.x;
    const int tid = threadIdx.x;
    const float* miou = miou_all + (size_t)b * NN;
    const float* sl1  = sl1_all  + (size_t)b * NN;
    const unsigned char* lbl = lbl_all + (size_t)b * NN;
    unsigned char* mask = mask_all + (size_t)b * NN;
    unsigned* list = list_all + (size_t)b * NN;

    __shared__ unsigned hist[2048];
    __shared__ int sh_s[3];
    __shared__ unsigned sh_u[2];
    __shared__ int wtot[16];
    __shared__ int sh_ties;
    __shared__ unsigned tieU[TIECAP];
    __shared__ int tieI[TIECAP];
    __shared__ int sh_tc;
    __shared__ int sh_lc;
    __shared__ float wred[16];

    const int pc = posCnt[b];
    const bool fallback = (pc < MINPOS);
    float accR = 0.0f;
    int np, kk;

    if (tid == 0) sh_lc = 0;

    if (!fallback) {
        np = pc;
        kk = NN - np; if (4 * np < kk) kk = 4 * np;

        // coarse pivot from precomputed histogram (candidate bins <= 503:
        // 0.5f == 0x3F000000 -> bin 504, boundary is exact)
        if (tid < 512) {
            unsigned v = gHist[b * 512 + tid];
            hist[tid] = (tid <= 503) ? v : 0u;
        }
        if (tid == 0) { sh_s[2] = kk; sh_tc = 0; }
        __syncthreads();
        scan_hist64(hist, 512, tid, sh_s);
        __syncthreads();
        const unsigned pivotBin = (unsigned)sh_s[0];
        if (tid == 0) sh_s[2] -= sh_s[1];
        hist[tid] = 0u; hist[tid + 1024] = 0u;
        __syncthreads();

        // one full-N histogram pass over bits [20:10] within the coarse bin
        for (int i = tid; i < NN; i += 1024) {
            unsigned u = __float_as_uint(miou[i]);
            if ((u >> 21) == pivotBin) atomicAdd(&hist[(u >> 10) & 2047u], 1u);
        }
        __syncthreads();
        scan_hist64(hist, 2048, tid, sh_s);
        __syncthreads();
        const unsigned pivot22 = (pivotBin << 11) | (unsigned)sh_s[0];
        const int rem = sh_s[2] - sh_s[1];   // ties (by value desc, idx asc) to accept

        // fused selection + compaction pass (no barriers inside)
        for (int i = tid; i < NN; i += 1024) {
            float v = miou[i];
            unsigned u = __float_as_uint(v);
            if (v >= 0.5f) {
                accR += sl1[i];
                int t = atomicAdd(&sh_lc, 1);
                list[t] = (unsigned)i | 0x10000u | ((unsigned)lbl[i] << 17);
            } else {
                unsigned p = u >> 10;
                if (p > pivot22) {
                    int t = atomicAdd(&sh_lc, 1);
                    list[t] = (unsigned)i;            // neg entry
                } else if (p == pivot22) {
                    int t = atomicAdd(&sh_tc, 1);
                    if (t < TIECAP) { tieU[t] = u; tieI[t] = i; }
                }
            }
        }
        __syncthreads();
        int tc = sh_tc; if (tc > TIECAP) tc = TIECAP;
        for (int t = tid; t < tc; t += 1024) {
            unsigned ut = tieU[t]; int it = tieI[t];
            int rank = 0;
            for (int j = 0; j < tc; ++j) {
                unsigned uj = tieU[j]; int ij = tieI[j];
                rank += (uj > ut || (uj == ut && ij < it)) ? 1 : 0;
            }
            if (rank < rem) {
                int t2 = atomicAdd(&sh_lc, 1);
                list[t2] = (unsigned)it;              // tie-accepted neg
            }
        }
    } else {
        // ---- fallback (pc < MINPOS) — R1-proven slow path, never hit here ----
        radix_select(miou, mask, 0, MINPOS, tid, hist, sh_s, sh_u);
        {
            const unsigned vb = sh_u[0];
            const int rem = sh_s[2];
            if (tid == 0) sh_ties = 0;
            __syncthreads();
            for (int base = 0; base < NN; base += 1024) {
                const int i = base + tid;
                const unsigned u = __float_as_uint(miou[i]);
                const bool tie = (u == vb);
                unsigned long long bal = __ballot(tie);
                const int wave = tid >> 6, lane = tid & 63;
                if (lane == 0) wtot[wave] = __popcll(bal);
                __syncthreads();
                int wexcl = 0;
                for (int wv = 0; wv < wave; ++wv) wexcl += wtot[wv];
                const int myexcl = sh_ties + wexcl + __popcll(bal & ((1ull << lane) - 1ull));
                const bool sel = (u > vb) || (tie && myexcl < rem);
                mask[i] = sel ? (unsigned char)1 : (unsigned char)0;
                __syncthreads();
                if (tid == 0) { int ts = 0; for (int wv = 0; wv < 16; ++wv) ts += wtot[wv]; sh_ties += ts; }
                __syncthreads();
            }
        }
        np = MINPOS;
        kk = NN - np; if (4 * np < kk) kk = 4 * np;
        radix_select(miou, mask, 2, kk, tid, hist, sh_s, sh_u);
        {
            const unsigned vb = sh_u[0];
            const int rem = sh_s[2];
            if (tid == 0) sh_ties = 0;
            __syncthreads();
            for (int base = 0; base < NN; base += 1024) {
                const int i = base + tid;
                const unsigned u = __float_as_uint(miou[i]);
                const bool pos = (mask[i] == (unsigned char)1);
                const bool cand = !pos;
                const bool tie = cand && (u == vb);
                unsigned long long bal = __ballot(tie);
                const int wave = tid >> 6, lane = tid & 63;
                if (lane == 0) wtot[wave] = __popcll(bal);
                __syncthreads();
                int wexcl = 0;
                for (int wv = 0; wv < wave; ++wv) wexcl += wtot[wv];
                const int myexcl = sh_ties + wexcl + __popcll(bal & ((1ull << lane) - 1ull));
                const bool neg = cand && ((u > vb) || (tie && myexcl < rem));
                mask[i] = pos ? (unsigned char)1 : (neg ? (unsigned char)2 : (unsigned char)0);
                __syncthreads();
                if (tid == 0) { int ts = 0; for (int wv = 0; wv < 16; ++wv) ts += wtot[wv]; sh_ties += ts; }
                __syncthreads();
            }
        }
        __syncthreads();
        for (int i = tid; i < NN; i += 1024) {
            unsigned char m = mask[i];
            if (m == (unsigned char)1) {
                accR += sl1[i];
                int t = atomicAdd(&sh_lc, 1);
                list[t] = (unsigned)i | 0x10000u | ((unsigned)lbl[i] << 17);
            } else if (m == (unsigned char)2) {
                int t = atomicAdd(&sh_lc, 1);
                list[t] = (unsigned)i;
            }
        }
    }

    // block-wide reduction of accR
    #pragma unroll
    for (int off = 32; off > 0; off >>= 1) accR += __shfl_down(accR, off);
    const int lane = tid & 63, wave = tid >> 6;
    if (lane == 0) wred[wave] = accR;
    __syncthreads();
    if (tid == 0) {
        float sR = 0.0f;
        for (int w = 0; w < 16; ++w) sR += wred[w];
        accum[b * 3 + 0] = 0.0f;     // pre-zero for k_cls2 atomics
        accum[b * 3 + 1] = 0.0f;
        accum[b * 3 + 2] = sR;
        numpos[b] = np;
        knum[b] = kk;
        listCnt[b] = sh_lc;
    }
}

// ------------------------------------------------------------------
// K3 (k_cls2): gather logsumexp ONLY for selected anchors.
// 4 threads per entry; grid (128, B); block-reduced atomics into accum.
// ------------------------------------------------------------------
__global__ __launch_bounds__(256) void k_cls2(
    const float* __restrict__ cls, const unsigned* __restrict__ list_all,
    const int* __restrict__ listCnt, float* __restrict__ accum)
{
    const int b   = blockIdx.y;
    const int n   = listCnt[b];
    const int al  = threadIdx.x >> 2;
    const int sub = threadIdx.x & 3;
    const unsigned* list = list_all + (size_t)b * NN;

    float aP = 0.0f, aN = 0.0f;
    for (int e = blockIdx.x * 64 + al; e < n; e += gridDim.x * 64) {
        unsigned ent = list[e];
        int a = (int)(ent & 0xFFFFu);
        size_t row = (size_t)b * NN + a;
        const float4* rowp = (const float4*)(cls + row * CC);
        float4 v0 = rowp[sub];
        float4 v1 = rowp[sub + 4];
        float4 v2 = rowp[sub + 8];
        float4 v3 = rowp[sub + 12];
        float4 v4 = rowp[sub + 16];
        float mx = fmaxf(fmaxf(fmaxf(v0.x, v0.y), fmaxf(v0.z, v0.w)),
                   fmaxf(fmaxf(fmaxf(v1.x, v1.y), fmaxf(v1.z, v1.w)),
                   fmaxf(fmaxf(fmaxf(v2.x, v2.y), fmaxf(v2.z, v2.w)),
                   fmaxf(fmaxf(fmaxf(v3.x, v3.y), fmaxf(v3.z, v3.w)),
                         fmaxf(fmaxf(v4.x, v4.y), fmaxf(v4.z, v4.w))))));
        float sm = expf(v0.x - mx) + expf(v0.y - mx) + expf(v0.z - mx) + expf(v0.w - mx)
                 + expf(v1.x - mx) + expf(v1.y - mx) + expf(v1.z - mx) + expf(v1.w - mx)
                 + expf(v2.x - mx) + expf(v2.y - mx) + expf(v2.z - mx) + expf(v2.w - mx)
                 + expf(v3.x - mx) + expf(v3.y - mx) + expf(v3.z - mx) + expf(v3.w - mx)
                 + expf(v4.x - mx) + expf(v4.y - mx) + expf(v4.z - mx) + expf(v4.w - mx);
        #pragma unroll
        for (int off = 1; off < 4; off <<= 1) {
            float m2 = __shfl_xor(mx, off);
            float s2 = __shfl_xor(sm, off);
            float nm = fmaxf(mx, m2);
            sm = sm * expf(mx - nm) + s2 * expf(m2 - nm);
            mx = nm;
        }
        if (sub == 0) {
            float lse = mx + logf(sm);
            if (ent & 0x10000u) {
                int lab = (int)((ent >> 17) & 0x7Fu);
                float ce = lse - cls[row * CC + lab];   // L1-hot reread
                float pt = expf(-ce);
                float o  = 1.0f - pt;
                aP += (lab > 0 ? 0.25f : 0.75f) * o * o * ce;
            } else {
                float ce = lse - v0.x;
                float pt = expf(-ce);
                float o  = 1.0f - pt;
                aN += 0.9f * o * o * o * ce;
            }
        }
    }

    // block reduce aP/aN -> 2 atomics per block
    #pragma unroll
    for (int off = 32; off > 0; off >>= 1) {
        aP += __shfl_down(aP, off);
        aN += __shfl_down(aN, off);
    }
    __shared__ float wp[4], wn[4];
    const int lane = threadIdx.x & 63, wave = threadIdx.x >> 6;
    if (lane == 0) { wp[wave] = aP; wn[wave] = aN; }
    __syncthreads();
    if (threadIdx.x == 0) {
        atomicAdd(&accum[b * 3 + 0], wp[0] + wp[1] + wp[2] + wp[3]);
        atomicAdd(&accum[b * 3 + 1], wn[0] + wn[1] + wn[2] + wn[3]);
    }
}

// ------------------------------------------------------------------
// K4: finalize the 4 scalar outputs.
// ------------------------------------------------------------------
__global__ void k_finalize(const float* __restrict__ accum,
                           const int* __restrict__ numpos,
                           const int* __restrict__ knum,
                           float* __restrict__ out)
{
    if (threadIdx.x == 0 && blockIdx.x == 0) {
        float clsf = 0.0f, regf = 0.0f;
        int tp = 0;
        for (int b = 0; b < BB; ++b) {
            float cp = accum[b * 3 + 0];
            float cn = accum[b * 3 + 1];
            float rs = accum[b * 3 + 2];
            int np = numpos[b], kk = knum[b];
            int ts = np + kk; if (ts < 1) ts = 1;
            clsf += (cp + cn) / (float)ts;
            regf += rs / ((float)np + 1e-6f);
            tp += np;
        }
        clsf *= (1.0f / BB);
        regf *= (1.0f / BB);
        float reg_final = (tp > 0) ? regf : 0.0f;
        float rw = fminf(1.0f, (float)tp / (100.0f * BB));
        out[0] = clsf + rw * reg_final;
        out[1] = clsf;
        out[2] = reg_final;
        out[3] = (float)tp;
    }
}

extern "C" void kernel_launch(void* const* d_in, const int* in_sizes, int n_in,
                              void* d_out, int out_size, void* d_ws, size_t ws_size,
                              hipStream_t stream)
{
    const float* cls     = (const float*)d_in[0];
    const float* reg     = (const float*)d_in[1];
    const float* anchors = (const float*)d_in[2];
    const float* tboxes  = (const float*)d_in[3];
    const int*   tlabels = (const int*)d_in[4];

    const size_t PL = (size_t)BB * NN * 4;   // one float plane = 2 MB
    char* ws = (char*)d_ws;
    float* sl1  = (float*)(ws);                                     // 2 MB
    float* miou = (float*)(ws + PL);                                // 2 MB
    unsigned* list = (unsigned*)(ws + 2 * PL);                      // 2 MB
    unsigned char* lbl  = (unsigned char*)(ws + 3 * PL);            // 512 KB
    unsigned char* mask = (unsigned char*)(ws + 3 * PL + PL / 4);   // 512 KB (fallback only)
    char* tail = ws + 3 * PL + PL / 2;
    unsigned* gHist = (unsigned*)tail;                // 8*512*4 = 16 KB
    int*   posCnt  = (int*)(tail + 16384);            // 32 B
    int*   listCnt = (int*)(tail + 16384 + 64);
    int*   numpos  = (int*)(tail + 16384 + 128);
    int*   knum    = (int*)(tail + 16384 + 192);
    float* accum   = (float*)(tail + 16384 + 256);
    float* out     = (float*)d_out;

    // gHist + posCnt must start zeroed (ws re-poisoned each launch)
    hipMemsetAsync(gHist, 0, 16384 + 64, stream);

    k_prep<<<dim3(NN / 256, BB), 256, 0, stream>>>(reg, anchors, tboxes, tlabels,
                                                   miou, sl1, lbl, gHist, posCnt);
    k_select<<<BB, 1024, 0, stream>>>(miou, sl1, lbl, gHist, posCnt, mask,
                                      list, listCnt, numpos, knum, accum);
    k_cls2<<<dim3(128, BB), 256, 0, stream>>>(cls, list, listCnt, accum);
    k_finalize<<<1, 64, 0, stream>>>(accum, numpos, knum, out);
}

// Round 4
// 301.474 us; speedup vs baseline: 1.4022x; 1.0862x over previous
//
#include <hip/hip_runtime.h>
#include <math.h>

#define BB 8
#define NN 65536
#define CC 80
#define TT 32
#define MINPOS 16
#define TIECAP 4096

__device__ __forceinline__ float frcp(float x) { return __builtin_amdgcn_rcpf(x); }

// ------------------------------------------------------------------
// K1 (k_prep): decode + IoU max only (no argmax/sl1 — recomputed later
// for the ~2.4K positives) + per-image posCnt + coarse 512-bin hist of
// miou float bits [31:21]. Grid (N/256, B). Division via v_rcp_f32.
// ------------------------------------------------------------------
__global__ __launch_bounds__(256) void k_prep(
    const float* __restrict__ reg, const float* __restrict__ anchors,
    const float* __restrict__ tboxes,
    float* __restrict__ miou_out, unsigned* __restrict__ gHist,
    int* __restrict__ posCnt)
{
    const int b   = blockIdx.y;
    const int tid = threadIdx.x;
    const int a   = blockIdx.x * 256 + tid;

    __shared__ float4 tb[TT];
    __shared__ float  tareaE[TT];
    __shared__ unsigned lh[512];
    __shared__ int    s_pc;

    if (tid < TT) {
        float4 t = ((const float4*)(tboxes + (size_t)b * TT * 4))[tid];
        tb[tid] = t;
        tareaE[tid] = (t.z - t.x) * (t.w - t.y) + 1e-6f;
    }
    lh[tid] = 0u; lh[tid + 256] = 0u;
    if (tid == 0) s_pc = 0;
    __syncthreads();

    float4 r  = ((const float4*)reg)[(size_t)b * NN + a];
    float4 an = ((const float4*)anchors)[a];
    float aw = an.z - an.x, ah = an.w - an.y;
    float acx = an.x + 0.5f * aw, acy = an.y + 0.5f * ah;
    float cx = r.x * aw + acx, cy = r.y * ah + acy;
    float w = expf(r.z) * aw, hh = expf(r.w) * ah;
    float dx0 = cx - 0.5f * w, dy0 = cy - 0.5f * hh;
    float dx1 = cx + 0.5f * w, dy1 = cy + 0.5f * hh;
    float areaA = (dx1 - dx0) * (dy1 - dy0);

    float mi = 0.0f;
    #pragma unroll 8
    for (int t = 0; t < TT; ++t) {
        float4 bx = tb[t];
        float ltx = fmaxf(dx0, bx.x), lty = fmaxf(dy0, bx.y);
        float rbx = fminf(dx1, bx.z), rby = fminf(dy1, bx.w);
        float iw = fmaxf(rbx - ltx, 0.0f), ih = fmaxf(rby - lty, 0.0f);
        float inter = iw * ih;
        float den = areaA + tareaE[t] - inter;
        float iou = inter * frcp(den);
        mi = fmaxf(mi, iou);
    }

    miou_out[(size_t)b * NN + a] = mi;
    atomicAdd(&lh[__float_as_uint(mi) >> 21], 1u);   // mi in [0,1] -> bin <= 508
    unsigned long long bal = __ballot(mi >= 0.5f);
    if ((tid & 63) == 0) atomicAdd(&s_pc, __popcll(bal));
    __syncthreads();

    if (lh[tid])       atomicAdd(&gHist[b * 512 + tid],       lh[tid]);
    if (lh[tid + 256]) atomicAdd(&gHist[b * 512 + tid + 256], lh[tid + 256]);
    if (tid == 0) atomicAdd(&posCnt[b], s_pc);
}

// ------------------------------------------------------------------
// scan over an LDS histogram: find bin d s.t. (count strictly above d)
// < need <= (count above + h[d]). sh_s[2]=need on entry; writes
// sh_s[0]=bin, sh_s[1]=count strictly above. Proven R1/R2/R3.
// Only threads 0..63 participate.
// ------------------------------------------------------------------
__device__ __forceinline__ void scan_hist64(unsigned* hist, int NB, int tid, int* sh_s)
{
    if (tid < 64) {
        const int cs = NB / 64;
        const int base = tid * cs;
        int csum = 0;
        for (int j = 0; j < cs; ++j) csum += (int)hist[base + j];
        int sfx = csum;
        #pragma unroll
        for (int off = 1; off < 64; off <<= 1) {
            int o = __shfl_down(sfx, off);
            if (tid + off < 64) sfx += o;
        }
        const int excl = sfx - csum;
        const int need = sh_s[2];
        int acc = excl;
        for (int j = cs - 1; j >= 0; --j) {
            int hcnt = (int)hist[base + j];
            int S = acc + hcnt;
            if (acc < need && S >= need) { sh_s[0] = base + j; sh_s[1] = acc; }
            acc = S;
        }
    }
}

// ------------------------------------------------------------------
// K2 (k_finehist): grid-parallel fine histogram (bits [20:10]) of the
// values inside the coarse pivot bin. Each block redundantly derives
// the coarse pivot from gHist (2 KB L2-hot), then scans its 2048-anchor
// chunk; matches are sparse -> direct global atomics. Grid (32, B).
// ------------------------------------------------------------------
__global__ __launch_bounds__(256) void k_finehist(
    const float* __restrict__ miou_all, const unsigned* __restrict__ gHist,
    const int* __restrict__ posCnt, unsigned* __restrict__ fineHist)
{
    const int b = blockIdx.y;
    const int tid = threadIdx.x;
    const int pc = posCnt[b];
    if (pc < MINPOS) return;                    // fallback path handles it
    const int np = pc;
    int kk = NN - np; if (4 * np < kk) kk = 4 * np;

    __shared__ unsigned hist[512];
    __shared__ int sh_s[3];
    hist[tid]       = (tid <= 503)       ? gHist[b * 512 + tid]       : 0u;
    hist[tid + 256] = (tid + 256 <= 503) ? gHist[b * 512 + tid + 256] : 0u;
    if (tid == 0) sh_s[2] = kk;
    __syncthreads();
    scan_hist64(hist, 512, tid, sh_s);
    __syncthreads();
    const unsigned pivotBin = (unsigned)sh_s[0];

    const float* miou = miou_all + (size_t)b * NN;
    const int base = blockIdx.x * 2048;
    for (int i = base + tid; i < base + 2048; i += 256) {
        unsigned u = __float_as_uint(miou[i]);
        if ((u >> 21) == pivotBin)
            atomicAdd(&fineHist[b * 2048 + ((u >> 10) & 2047u)], 1u);
    }
}

// ------------------------------------------------------------------
// K3 (k_compact): grid-parallel selection + compaction. Each block
// redundantly derives coarse+fine pivots (10 KB L2-hot), classifies its
// 2048 anchors, stages list entries in LDS, reserves a range with ONE
// global atomic, and copies out. Positives recompute argmax/sl1/label
// here (bit-identical IoU expression to k_prep). Grid (32, B).
// ------------------------------------------------------------------
__global__ __launch_bounds__(256) void k_compact(
    const float* __restrict__ reg, const float* __restrict__ anchors,
    const float* __restrict__ tboxes, const int* __restrict__ tlabels,
    const float* __restrict__ miou_all,
    const unsigned* __restrict__ gHist, const unsigned* __restrict__ fineHist,
    const int* __restrict__ posCnt,
    unsigned* __restrict__ list_all, int* __restrict__ listCnt,
    unsigned* __restrict__ tieU_all, int* __restrict__ tieI_all,
    int* __restrict__ tieCnt,
    int* __restrict__ numpos, int* __restrict__ knum, float* __restrict__ accum)
{
    const int b = blockIdx.y;
    const int tid = threadIdx.x;
    const int pc = posCnt[b];
    if (pc < MINPOS) return;                    // fallback path handles it
    const int np = pc;
    int kk = NN - np; if (4 * np < kk) kk = 4 * np;

    __shared__ float4 tb[TT];
    __shared__ float  tareaE[TT];
    __shared__ int    tl[TT];
    __shared__ unsigned hist[2048];
    __shared__ unsigned lbuf[2048];
    __shared__ int sh_s[3];
    __shared__ int sh_cnt, sh_base;
    __shared__ float wred[4];

    if (tid < TT) {
        float4 t = ((const float4*)(tboxes + (size_t)b * TT * 4))[tid];
        tb[tid] = t;
        tareaE[tid] = (t.z - t.x) * (t.w - t.y) + 1e-6f;
        tl[tid] = tlabels[b * TT + tid];
    }
    // coarse pivot
    hist[tid]       = (tid <= 503)       ? gHist[b * 512 + tid]       : 0u;
    hist[tid + 256] = (tid + 256 <= 503) ? gHist[b * 512 + tid + 256] : 0u;
    if (tid == 0) { sh_s[2] = kk; sh_cnt = 0; }
    __syncthreads();
    scan_hist64(hist, 512, tid, sh_s);
    __syncthreads();
    const unsigned pivotBin = (unsigned)sh_s[0];
    const int needB = kk - sh_s[1];
    __syncthreads();
    // fine pivot
    for (int k = tid; k < 2048; k += 256) hist[k] = fineHist[b * 2048 + k];
    if (tid == 0) sh_s[2] = needB;
    __syncthreads();
    scan_hist64(hist, 2048, tid, sh_s);
    __syncthreads();
    const unsigned pivot22 = (pivotBin << 11) | (unsigned)sh_s[0];

    float accR = 0.0f;
    const float* miou = miou_all + (size_t)b * NN;
    const int base = blockIdx.x * 2048;
    for (int i = base + tid; i < base + 2048; i += 256) {
        float v = miou[i];
        unsigned u = __float_as_uint(v);
        if (v >= 0.5f) {
            // recompute argmax (bit-identical IoU) + sl1 + label
            float4 r  = ((const float4*)reg)[(size_t)b * NN + i];
            float4 an = ((const float4*)anchors)[i];
            float aw = an.z - an.x, ah = an.w - an.y;
            float acx = an.x + 0.5f * aw, acy = an.y + 0.5f * ah;
            float cx = r.x * aw + acx, cy = r.y * ah + acy;
            float w = expf(r.z) * aw, hh2 = expf(r.w) * ah;
            float dx0 = cx - 0.5f * w, dy0 = cy - 0.5f * hh2;
            float dx1 = cx + 0.5f * w, dy1 = cy + 0.5f * hh2;
            float areaA = (dx1 - dx0) * (dy1 - dy0);
            float mi = 0.0f; int mix = 0;
            #pragma unroll 8
            for (int t = 0; t < TT; ++t) {
                float4 bx = tb[t];
                float ltx = fmaxf(dx0, bx.x), lty = fmaxf(dy0, bx.y);
                float rbx = fminf(dx1, bx.z), rby = fminf(dy1, bx.w);
                float iw = fmaxf(rbx - ltx, 0.0f), ih = fmaxf(rby - lty, 0.0f);
                float inter = iw * ih;
                float den = areaA + tareaE[t] - inter;
                float iou = inter * frcp(den);
                if (iou > mi) { mi = iou; mix = t; }
            }
            float4 gt = tb[mix];
            float gw = gt.z - gt.x, gh = gt.w - gt.y;
            float gcx = gt.x + 0.5f * gw, gcy = gt.y + 0.5f * gh;
            float t0 = (gcx - acx) / (aw + 1e-6f);
            float t1 = (gcy - acy) / (ah + 1e-6f);
            float t2 = logf(gw / (aw + 1e-6f));
            float t3 = logf(gh / (ah + 1e-6f));
            float d0 = fabsf(r.x - t0), d1 = fabsf(r.y - t1);
            float d2 = fabsf(r.z - t2), d3 = fabsf(r.w - t3);
            accR += (d0 < 1.0f ? 0.5f * d0 * d0 : d0 - 0.5f)
                  + (d1 < 1.0f ? 0.5f * d1 * d1 : d1 - 0.5f)
                  + (d2 < 1.0f ? 0.5f * d2 * d2 : d2 - 0.5f)
                  + (d3 < 1.0f ? 0.5f * d3 * d3 : d3 - 0.5f);
            int t4 = atomicAdd(&sh_cnt, 1);
            lbuf[t4] = (unsigned)i | 0x10000u | ((unsigned)tl[mix] << 17);
        } else {
            unsigned p = u >> 10;
            if (p > pivot22) {
                int t = atomicAdd(&sh_cnt, 1);
                lbuf[t] = (unsigned)i;
            } else if (p == pivot22) {
                int t = atomicAdd(&tieCnt[b], 1);
                if (t < TIECAP) {
                    tieU_all[b * TIECAP + t] = u;
                    tieI_all[b * TIECAP + t] = i;
                }
            }
        }
    }
    __syncthreads();
    const int cnt = sh_cnt;
    if (tid == 0) sh_base = atomicAdd(&listCnt[b], cnt);
    __syncthreads();
    unsigned* list = list_all + (size_t)b * NN;
    for (int k = tid; k < cnt; k += 256) list[sh_base + k] = lbuf[k];

    #pragma unroll
    for (int off = 32; off > 0; off >>= 1) accR += __shfl_down(accR, off);
    const int lane = tid & 63, wave = tid >> 6;
    if (lane == 0) wred[wave] = accR;
    __syncthreads();
    if (tid == 0) {
        atomicAdd(&accum[b * 3 + 2], wred[0] + wred[1] + wred[2] + wred[3]);
        if (blockIdx.x == 0) { numpos[b] = np; knum[b] = kk; }
    }
}

// ------------------------------------------------------------------
// K4 (k_tierank): rank the few pivot-bin ties (value desc, index asc),
// append accepted negatives to the list. Grid (B) x 256.
// ------------------------------------------------------------------
__global__ __launch_bounds__(256) void k_tierank(
    const unsigned* __restrict__ gHist, const unsigned* __restrict__ fineHist,
    const int* __restrict__ posCnt,
    const unsigned* __restrict__ tieU_all, const int* __restrict__ tieI_all,
    const int* __restrict__ tieCnt,
    unsigned* __restrict__ list_all, int* __restrict__ listCnt)
{
    const int b = blockIdx.x;
    const int tid = threadIdx.x;
    const int pc = posCnt[b];
    if (pc < MINPOS) return;
    const int np = pc;
    int kk = NN - np; if (4 * np < kk) kk = 4 * np;

    __shared__ unsigned hist[2048];
    __shared__ int sh_s[3];
    __shared__ unsigned tu[TIECAP];
    __shared__ int ti[TIECAP];

    hist[tid]       = (tid <= 503)       ? gHist[b * 512 + tid]       : 0u;
    hist[tid + 256] = (tid + 256 <= 503) ? gHist[b * 512 + tid + 256] : 0u;
    if (tid == 0) sh_s[2] = kk;
    __syncthreads();
    scan_hist64(hist, 512, tid, sh_s);
    __syncthreads();
    const int needB = kk - sh_s[1];
    __syncthreads();
    for (int k = tid; k < 2048; k += 256) hist[k] = fineHist[b * 2048 + k];
    if (tid == 0) sh_s[2] = needB;
    __syncthreads();
    scan_hist64(hist, 2048, tid, sh_s);
    __syncthreads();
    const int rem = needB - sh_s[1];     // ties to accept

    int c = tieCnt[b]; if (c > TIECAP) c = TIECAP;
    for (int k = tid; k < c; k += 256) {
        tu[k] = tieU_all[b * TIECAP + k];
        ti[k] = tieI_all[b * TIECAP + k];
    }
    __syncthreads();
    unsigned* list = list_all + (size_t)b * NN;
    for (int t = tid; t < c; t += 256) {
        unsigned ut = tu[t]; int it = ti[t];
        int rank = 0;
        for (int j = 0; j < c; ++j) {
            unsigned uj = tu[j]; int ij = ti[j];
            rank += (uj > ut || (uj == ut && ij < it)) ? 1 : 0;
        }
        if (rank < rem) {
            int p = atomicAdd(&listCnt[b], 1);
            list[p] = (unsigned)it;
        }
    }
}

// R1-proven 3-round radix select (fallback path only).
__device__ __forceinline__ void radix_select(
    const float* __restrict__ vals, const unsigned char* __restrict__ mask,
    int mode, int kk, int tid,
    unsigned* hist, int* sh_s, unsigned* sh_u)
{
    if (tid == 0) { sh_u[0] = 0u; sh_u[1] = 0u; sh_s[2] = kk; }
    __syncthreads();
    #pragma unroll
    for (int rnd = 0; rnd < 3; ++rnd) {
        const int sh = (rnd == 0) ? 21 : ((rnd == 1) ? 10 : 0);
        const int NB = (rnd == 2) ? 1024 : 2048;
        hist[tid] = 0u; hist[tid + 1024] = 0u;
        __syncthreads();
        const unsigned pref = sh_u[0], pmask = sh_u[1];
        for (int i = tid; i < NN; i += 1024) {
            bool c = (mode == 0) ? true : (mask[i] != (unsigned char)1);
            if (c) {
                unsigned u = __float_as_uint(vals[i]);
                if ((u & pmask) == pref)
                    atomicAdd(&hist[(u >> sh) & (unsigned)(NB - 1)], 1u);
            }
        }
        __syncthreads();
        scan_hist64(hist, NB, tid, sh_s);
        __syncthreads();
        if (tid == 0) {
            sh_u[0] |= ((unsigned)sh_s[0]) << sh;
            sh_u[1] |= ((unsigned)(NB - 1)) << sh;
            sh_s[2] -= sh_s[1];
        }
        __syncthreads();
    }
}

// ------------------------------------------------------------------
// K5 (k_fallback): full slow path, only if posCnt[b] < MINPOS (never
// hit with this data — early-returns in ~2 us). Grid (B) x 1024.
// ------------------------------------------------------------------
__global__ __launch_bounds__(1024) void k_fallback(
    const float* __restrict__ reg, const float* __restrict__ anchors,
    const float* __restrict__ tboxes, const int* __restrict__ tlabels,
    const float* __restrict__ miou_all, unsigned char* __restrict__ mask_all,
    const int* __restrict__ posCnt,
    unsigned* __restrict__ list_all, int* __restrict__ listCnt,
    int* __restrict__ numpos, int* __restrict__ knum, float* __restrict__ accum)
{
    const int b = blockIdx.x;
    const int tid = threadIdx.x;
    if (posCnt[b] >= MINPOS) return;

    const float* miou = miou_all + (size_t)b * NN;
    unsigned char* mask = mask_all + (size_t)b * NN;
    unsigned* list = list_all + (size_t)b * NN;

    __shared__ float4 tb[TT];
    __shared__ float  tareaE[TT];
    __shared__ int    tl[TT];
    __shared__ unsigned hist[2048];
    __shared__ int sh_s[3];
    __shared__ unsigned sh_u[2];
    __shared__ int wtot[16];
    __shared__ int sh_ties;
    __shared__ float wred[16];

    if (tid < TT) {
        float4 t = ((const float4*)(tboxes + (size_t)b * TT * 4))[tid];
        tb[tid] = t;
        tareaE[tid] = (t.z - t.x) * (t.w - t.y) + 1e-6f;
        tl[tid] = tlabels[b * TT + tid];
    }
    __syncthreads();

    // top-16 over all anchors, stable (index-order) ties -> mask=1
    radix_select(miou, mask, 0, MINPOS, tid, hist, sh_s, sh_u);
    {
        const unsigned vb = sh_u[0];
        const int rem = sh_s[2];
        if (tid == 0) sh_ties = 0;
        __syncthreads();
        for (int base = 0; base < NN; base += 1024) {
            const int i = base + tid;
            const unsigned u = __float_as_uint(miou[i]);
            const bool tie = (u == vb);
            unsigned long long bal = __ballot(tie);
            const int wave = tid >> 6, lane = tid & 63;
            if (lane == 0) wtot[wave] = __popcll(bal);
            __syncthreads();
            int wexcl = 0;
            for (int wv = 0; wv < wave; ++wv) wexcl += wtot[wv];
            const int myexcl = sh_ties + wexcl + __popcll(bal & ((1ull << lane) - 1ull));
            const bool sel = (u > vb) || (tie && myexcl < rem);
            mask[i] = sel ? (unsigned char)1 : (unsigned char)0;
            __syncthreads();
            if (tid == 0) { int ts = 0; for (int wv = 0; wv < 16; ++wv) ts += wtot[wv]; sh_ties += ts; }
            __syncthreads();
        }
    }
    const int np = MINPOS;
    int kk = NN - np; if (4 * np < kk) kk = 4 * np;
    radix_select(miou, mask, 2, kk, tid, hist, sh_s, sh_u);
    {
        const unsigned vb = sh_u[0];
        const int rem = sh_s[2];
        if (tid == 0) sh_ties = 0;
        __syncthreads();
        for (int base = 0; base < NN; base += 1024) {
            const int i = base + tid;
            const unsigned u = __float_as_uint(miou[i]);
            const bool pos = (mask[i] == (unsigned char)1);
            const bool cand = !pos;
            const bool tie = cand && (u == vb);
            unsigned long long bal = __ballot(tie);
            const int wave = tid >> 6, lane = tid & 63;
            if (lane == 0) wtot[wave] = __popcll(bal);
            __syncthreads();
            int wexcl = 0;
            for (int wv = 0; wv < wave; ++wv) wexcl += wtot[wv];
            const int myexcl = sh_ties + wexcl + __popcll(bal & ((1ull << lane) - 1ull));
            const bool neg = cand && ((u > vb) || (tie && myexcl < rem));
            mask[i] = pos ? (unsigned char)1 : (neg ? (unsigned char)2 : (unsigned char)0);
            __syncthreads();
            if (tid == 0) { int ts = 0; for (int wv = 0; wv < 16; ++wv) ts += wtot[wv]; sh_ties += ts; }
            __syncthreads();
        }
    }

    float accR = 0.0f;
    for (int i = tid; i < NN; i += 1024) {
        unsigned char m = mask[i];
        if (m == (unsigned char)1) {
            float4 r  = ((const float4*)reg)[(size_t)b * NN + i];
            float4 an = ((const float4*)anchors)[i];
            float aw = an.z - an.x, ah = an.w - an.y;
            float acx = an.x + 0.5f * aw, acy = an.y + 0.5f * ah;
            float cx = r.x * aw + acx, cy = r.y * ah + acy;
            float w = expf(r.z) * aw, hh2 = expf(r.w) * ah;
            float dx0 = cx - 0.5f * w, dy0 = cy - 0.5f * hh2;
            float dx1 = cx + 0.5f * w, dy1 = cy + 0.5f * hh2;
            float areaA = (dx1 - dx0) * (dy1 - dy0);
            float mi = 0.0f; int mix = 0;
            for (int t = 0; t < TT; ++t) {
                float4 bx = tb[t];
                float ltx = fmaxf(dx0, bx.x), lty = fmaxf(dy0, bx.y);
                float rbx = fminf(dx1, bx.z), rby = fminf(dy1, bx.w);
                float iw = fmaxf(rbx - ltx, 0.0f), ih = fmaxf(rby - lty, 0.0f);
                float inter = iw * ih;
                float den = areaA + tareaE[t] - inter;
                float iou = inter * frcp(den);
                if (iou > mi) { mi = iou; mix = t; }
            }
            float4 gt = tb[mix];
            float gw = gt.z - gt.x, gh = gt.w - gt.y;
            float gcx = gt.x + 0.5f * gw, gcy = gt.y + 0.5f * gh;
            float t0 = (gcx - acx) / (aw + 1e-6f);
            float t1 = (gcy - acy) / (ah + 1e-6f);
            float t2 = logf(gw / (aw + 1e-6f));
            float t3 = logf(gh / (ah + 1e-6f));
            float d0 = fabsf(r.x - t0), d1 = fabsf(r.y - t1);
            float d2 = fabsf(r.z - t2), d3 = fabsf(r.w - t3);
            accR += (d0 < 1.0f ? 0.5f * d0 * d0 : d0 - 0.5f)
                  + (d1 < 1.0f ? 0.5f * d1 * d1 : d1 - 0.5f)
                  + (d2 < 1.0f ? 0.5f * d2 * d2 : d2 - 0.5f)
                  + (d3 < 1.0f ? 0.5f * d3 * d3 : d3 - 0.5f);
            int t = atomicAdd(&listCnt[b], 1);
            list[t] = (unsigned)i | 0x10000u | ((unsigned)tl[mix] << 17);
        } else if (m == (unsigned char)2) {
            int t = atomicAdd(&listCnt[b], 1);
            list[t] = (unsigned)i;
        }
    }

    #pragma unroll
    for (int off = 32; off > 0; off >>= 1) accR += __shfl_down(accR, off);
    const int lane = tid & 63, wave = tid >> 6;
    if (lane == 0) wred[wave] = accR;
    __syncthreads();
    if (tid == 0) {
        float sR = 0.0f;
        for (int w = 0; w < 16; ++w) sR += wred[w];
        accum[b * 3 + 2] = sR;
        numpos[b] = np;
        knum[b] = kk;
    }
}

// ------------------------------------------------------------------
// K6 (k_cls2): gather logsumexp ONLY for selected anchors.
// 4 threads per entry; grid (128, B); block-reduced atomics into accum.
// ------------------------------------------------------------------
__global__ __launch_bounds__(256) void k_cls2(
    const float* __restrict__ cls, const unsigned* __restrict__ list_all,
    const int* __restrict__ listCnt, float* __restrict__ accum)
{
    const int b   = blockIdx.y;
    const int n   = listCnt[b];
    const int al  = threadIdx.x >> 2;
    const int sub = threadIdx.x & 3;
    const unsigned* list = list_all + (size_t)b * NN;

    float aP = 0.0f, aN = 0.0f;
    for (int e = blockIdx.x * 64 + al; e < n; e += gridDim.x * 64) {
        unsigned ent = list[e];
        int a = (int)(ent & 0xFFFFu);
        size_t row = (size_t)b * NN + a;
        const float4* rowp = (const float4*)(cls + row * CC);
        float4 v0 = rowp[sub];
        float4 v1 = rowp[sub + 4];
        float4 v2 = rowp[sub + 8];
        float4 v3 = rowp[sub + 12];
        float4 v4 = rowp[sub + 16];
        float mx = fmaxf(fmaxf(fmaxf(v0.x, v0.y), fmaxf(v0.z, v0.w)),
                   fmaxf(fmaxf(fmaxf(v1.x, v1.y), fmaxf(v1.z, v1.w)),
                   fmaxf(fmaxf(fmaxf(v2.x, v2.y), fmaxf(v2.z, v2.w)),
                   fmaxf(fmaxf(fmaxf(v3.x, v3.y), fmaxf(v3.z, v3.w)),
                         fmaxf(fmaxf(v4.x, v4.y), fmaxf(v4.z, v4.w))))));
        float sm = expf(v0.x - mx) + expf(v0.y - mx) + expf(v0.z - mx) + expf(v0.w - mx)
                 + expf(v1.x - mx) + expf(v1.y - mx) + expf(v1.z - mx) + expf(v1.w - mx)
                 + expf(v2.x - mx) + expf(v2.y - mx) + expf(v2.z - mx) + expf(v2.w - mx)
                 + expf(v3.x - mx) + expf(v3.y - mx) + expf(v3.z - mx) + expf(v3.w - mx)
                 + expf(v4.x - mx) + expf(v4.y - mx) + expf(v4.z - mx) + expf(v4.w - mx);
        #pragma unroll
        for (int off = 1; off < 4; off <<= 1) {
            float m2 = __shfl_xor(mx, off);
            float s2 = __shfl_xor(sm, off);
            float nm = fmaxf(mx, m2);
            sm = sm * expf(mx - nm) + s2 * expf(m2 - nm);
            mx = nm;
        }
        if (sub == 0) {
            float lse = mx + logf(sm);
            if (ent & 0x10000u) {
                int lab = (int)((ent >> 17) & 0xFFu);
                float ce = lse - cls[row * CC + lab];   // L1-hot reread
                float pt = expf(-ce);
                float o  = 1.0f - pt;
                aP += (lab > 0 ? 0.25f : 0.75f) * o * o * ce;
            } else {
                float ce = lse - v0.x;
                float pt = expf(-ce);
                float o  = 1.0f - pt;
                aN += 0.9f * o * o * o * ce;
            }
        }
    }

    #pragma unroll
    for (int off = 32; off > 0; off >>= 1) {
        aP += __shfl_down(aP, off);
        aN += __shfl_down(aN, off);
    }
    __shared__ float wp[4], wn[4];
    const int lane = threadIdx.x & 63, wave = threadIdx.x >> 6;
    if (lane == 0) { wp[wave] = aP; wn[wave] = aN; }
    __syncthreads();
    if (threadIdx.x == 0) {
        atomicAdd(&accum[b * 3 + 0], wp[0] + wp[1] + wp[2] + wp[3]);
        atomicAdd(&accum[b * 3 + 1], wn[0] + wn[1] + wn[2] + wn[3]);
    }
}

// ------------------------------------------------------------------
// K7: finalize the 4 scalar outputs.
// ------------------------------------------------------------------
__global__ void k_finalize(const float* __restrict__ accum,
                           const int* __restrict__ numpos,
                           const int* __restrict__ knum,
                           float* __restrict__ out)
{
    if (threadIdx.x == 0 && blockIdx.x == 0) {
        float clsf = 0.0f, regf = 0.0f;
        int tp = 0;
        for (int b = 0; b < BB; ++b) {
            float cp = accum[b * 3 + 0];
            float cn = accum[b * 3 + 1];
            float rs = accum[b * 3 + 2];
            int np = numpos[b], kk = knum[b];
            int ts = np + kk; if (ts < 1) ts = 1;
            clsf += (cp + cn) / (float)ts;
            regf += rs / ((float)np + 1e-6f);
            tp += np;
        }
        clsf *= (1.0f / BB);
        regf *= (1.0f / BB);
        float reg_final = (tp > 0) ? regf : 0.0f;
        float rw = fminf(1.0f, (float)tp / (100.0f * BB));
        out[0] = clsf + rw * reg_final;
        out[1] = clsf;
        out[2] = reg_final;
        out[3] = (float)tp;
    }
}

extern "C" void kernel_launch(void* const* d_in, const int* in_sizes, int n_in,
                              void* d_out, int out_size, void* d_ws, size_t ws_size,
                              hipStream_t stream)
{
    const float* cls     = (const float*)d_in[0];
    const float* reg     = (const float*)d_in[1];
    const float* anchors = (const float*)d_in[2];
    const float* tboxes  = (const float*)d_in[3];
    const int*   tlabels = (const int*)d_in[4];

    const size_t PL = (size_t)BB * NN * 4;   // one float plane = 2 MB
    char* ws = (char*)d_ws;
    float*    miou = (float*)(ws);                         // 2 MB
    unsigned* list = (unsigned*)(ws + PL);                 // 2 MB
    unsigned char* mask = (unsigned char*)(ws + 2 * PL);   // 512 KB (fallback only)
    unsigned* tieU = (unsigned*)(ws + 2 * PL + PL / 4);    // 128 KB
    int*      tieI = (int*)(ws + 2 * PL + PL / 4 + (size_t)BB * TIECAP * 4); // 128 KB
    char* Z = ws + 2 * PL + PL / 4 + 2 * (size_t)BB * TIECAP * 4;
    unsigned* gHist    = (unsigned*)Z;                     // 16 KB
    unsigned* fineHist = (unsigned*)(Z + 16384);           // 64 KB
    char* ctr = Z + 16384 + 65536;
    int*   posCnt  = (int*)(ctr);
    int*   listCnt = (int*)(ctr + 32);
    int*   tieCnt  = (int*)(ctr + 64);
    int*   numpos  = (int*)(ctr + 96);
    int*   knum    = (int*)(ctr + 128);
    float* accum   = (float*)(ctr + 160);                  // 24 floats
    float* out     = (float*)d_out;

    // gHist + fineHist + all counters/accum must start zeroed
    hipMemsetAsync(Z, 0, 16384 + 65536 + 256, stream);

    k_prep<<<dim3(NN / 256, BB), 256, 0, stream>>>(reg, anchors, tboxes,
                                                   miou, gHist, posCnt);
    k_finehist<<<dim3(32, BB), 256, 0, stream>>>(miou, gHist, posCnt, fineHist);
    k_compact<<<dim3(32, BB), 256, 0, stream>>>(reg, anchors, tboxes, tlabels,
                                                miou, gHist, fineHist, posCnt,
                                                list, listCnt, tieU, tieI, tieCnt,
                                                numpos, knum, accum);
    k_tierank<<<BB, 256, 0, stream>>>(gHist, fineHist, posCnt, tieU, tieI, tieCnt,
                                      list, listCnt);
    k_fallback<<<BB, 1024, 0, stream>>>(reg, anchors, tboxes, tlabels, miou, mask,
                                        posCnt, list, listCnt, numpos, knum, accum);
    k_cls2<<<dim3(128, BB), 256, 0, stream>>>(cls, list, listCnt, accum);
    k_finalize<<<1, 64, 0, stream>>>(accum, numpos, knum, out);
}